// Round 9
// baseline (198.036 us; speedup 1.0000x reference)
//
#include <hip/hip_runtime.h>
#include <math.h>

// Problem constants (fixed by reference setup_inputs)
constexpr int B = 32, C = 512, N = 1024;   // N = H*W

typedef float f32x4 __attribute__((ext_vector_type(4)));
typedef _Float16 f16x8 __attribute__((ext_vector_type(8)));
typedef unsigned short u16x4 __attribute__((ext_vector_type(4)));

// fp16 bit helpers
__device__ __forceinline__ unsigned short f32_to_f16u(float v) {
  union { _Float16 h; unsigned short u; } cv; cv.h = (_Float16)v; return cv.u;
}
__device__ __forceinline__ float f16u_to_f32(unsigned short u) {
  union { _Float16 h; unsigned short u; } cv; cv.u = u; return (float)cv.h;
}

// async global->LDS, 16B per lane; LDS dest = wave-uniform base + lane*16
__device__ __forceinline__ void glds16(const void* g, void* l) {
  __builtin_amdgcn_global_load_lds((const __attribute__((address_space(1))) void*)g,
                                   (__attribute__((address_space(3))) void*)l, 16, 0, 0);
}

// ---------------------------------------------------------------------------
// Kernel 0: x (fp32 [B,C,N]) -> fp16 xf [B,C,N] and transposed xfT [B,N,C].
// 64x64 tiles, float4 loads, LDS transpose.  (unchanged — already ~mem-bound)
// ---------------------------------------------------------------------------
__global__ __launch_bounds__(256) void convert_kernel(const float* __restrict__ x,
                                                      unsigned short* __restrict__ xf,
                                                      unsigned short* __restrict__ xfT) {
  const int b = blockIdx.z;
  const int cy = blockIdx.y * 64;   // C tile origin
  const int nx = blockIdx.x * 64;   // N tile origin
  const int t = threadIdx.x;
  const int r = t >> 4, c4 = (t & 15) * 4;

  __shared__ unsigned T[64][65];    // u32 slots: 2-way-max banking both phases

#pragma unroll
  for (int rr = 0; rr < 64; rr += 16) {
    const int row = rr + r;
    const size_t gi = ((size_t)b * C + cy + row) * N + nx + c4;
    const float4 v = *(const float4*)&x[gi];
    u16x4 h;
    h[0] = f32_to_f16u(v.x); h[1] = f32_to_f16u(v.y);
    h[2] = f32_to_f16u(v.z); h[3] = f32_to_f16u(v.w);
    *(u16x4*)&xf[gi] = h;
    T[row][c4 + 0] = h[0]; T[row][c4 + 1] = h[1];
    T[row][c4 + 2] = h[2]; T[row][c4 + 3] = h[3];
  }
  __syncthreads();
#pragma unroll
  for (int rr = 0; rr < 64; rr += 16) {
    const int nrow = rr + r;
    u16x4 o;
    o[0] = (unsigned short)T[c4 + 0][nrow]; o[1] = (unsigned short)T[c4 + 1][nrow];
    o[2] = (unsigned short)T[c4 + 2][nrow]; o[3] = (unsigned short)T[c4 + 3][nrow];
    *(u16x4*)&xfT[((size_t)b * N + nx + nrow) * C + cy + c4] = o;
  }
}

// ---------------------------------------------------------------------------
// Kernel 1 (FUSED, 2 BLOCKS/CU): 32-row tiles, 512 blocks.  G rows -> softmax
// -> A to GLOBAL (32 KB/block, L2-hot, same-CU glds read-back) -> E=A*F ->
// out = beta*E + x.  LDS 69 KB (B-dbuf 64 + A-dbuf 4 + red 1.2) -> 2 resident
// blocks/CU = 4 waves/SIMD: one block's compute fills the other's barrier
// drains (the mechanism every 1-block/CU variant lacked; all were 65-77 us,
// MfmaUtil 20%, all pipes idle).  Simple m97-style K-loop: one __syncthreads
// per K-step, glds stage-ahead.  8 waves x (32x64) tile, 2x4 frags, 8 MFMA.
// ---------------------------------------------------------------------------
__global__ __launch_bounds__(512, 4) void gram_soft_av(const unsigned short* __restrict__ xf,
                                                       const unsigned short* __restrict__ xfT,
                                                       unsigned short* __restrict__ Aw,
                                                       const float* __restrict__ beta,
                                                       float* __restrict__ out) {
  const int l = blockIdx.x;
  const int xcd = l & 7, seq = l >> 3;     // 64 blocks per XCD
  const int b = xcd + 8 * (seq >> 4);      // 4 batch-groups per XCD (L2 reuse)
  const int i0 = (seq & 15) * 32;          // row-tile origin (16 tiles of 32)

  const unsigned short* __restrict__ Fh = xf  + (size_t)b * C * N;
  const unsigned short* __restrict__ FT = xfT + (size_t)b * N * C;
  float* __restrict__ ob = out + (size_t)b * C * N;
  unsigned short* __restrict__ Ag = Aw + (size_t)b * C * C + (size_t)i0 * C; // 32 rows

  __shared__ __align__(16) unsigned short Pb[2][512 * 32];   // 64 KB B-staging
  __shared__ __align__(16) unsigned short Asb[2][32 * 32];   // 4 KB A-staging
  __shared__ float red[256];                                 // 8 waves x 32 rows
  __shared__ float fin[32];

  const int t = threadIdx.x, wave = t >> 6, lane = t & 63;   // 8 waves
  const int lrow = lane & 15, quad = lane >> 4;
  const int srow = lane >> 2;                              // row in 16-row chunk
  const int sel  = ((lane & 3) ^ ((lane >> 3) & 3)) * 8;   // swizzled src granule

  f32x4 acc[2][4] = {};   // wave tile 32x64: [ti 2 row-frags][tj 4 col-frags]

#define MFMA8(AH, BH, ACC)                                                \
  {                                                                       \
    __builtin_amdgcn_s_setprio(1);                                        \
    _Pragma("unroll")                                                     \
    for (int ti = 0; ti < 2; ++ti)                                        \
      _Pragma("unroll")                                                   \
      for (int tj = 0; tj < 4; ++tj)                                      \
        ACC[ti][tj] = __builtin_amdgcn_mfma_f32_16x16x32_f16(AH[ti], BH[tj], ACC[ti][tj], 0, 0, 0); \
    __builtin_amdgcn_s_setprio(0);                                        \
  }

  // ========================= Phase 1: Gram rows = F F^T ======================
  // B-panel: all 512 F-rows x 32 cols staged per K-step (A rows are a subset).
#define STAGE1(k0, nb)                                                    \
  {                                                                       \
    _Pragma("unroll")                                                     \
    for (int cc = 0; cc < 4; ++cc) {                                      \
      const int chunk = wave * 4 + cc;                                    \
      const int row = chunk * 16 + srow;                                  \
      glds16(Fh + (size_t)row * N + (k0) + sel, &Pb[nb][chunk * 512]);    \
    }                                                                     \
  }

  STAGE1(0, 0);
  for (int it = 0; it < 32; ++it) {
    __syncthreads();                       // stage(it) landed; prev reads done
    if (it + 1 < 32) STAGE1((it + 1) * 32, (it + 1) & 1);
    const unsigned short* __restrict__ Pc = Pb[it & 1];
    f16x8 ah[2], bh[4];
#pragma unroll
    for (int ti = 0; ti < 2; ++ti) {
      const int r = i0 + ti * 16 + lrow;
      ah[ti] = *(const f16x8*)&Pc[r * 32 + (quad ^ ((r >> 1) & 3)) * 8];
    }
#pragma unroll
    for (int tj = 0; tj < 4; ++tj) {
      const int r = wave * 64 + tj * 16 + lrow;
      bh[tj] = *(const f16x8*)&Pc[r * 32 + (quad ^ ((r >> 1) & 3)) * 8];
    }
    MFMA8(ah, bh, acc);
  }
#undef STAGE1

  // ==================== fused softmax (32 rows complete in block) ============
  // Wave holds rows ti*16+quad*4+rr (ti<2) x its 64-col strip.
  float m[8];
#pragma unroll
  for (int ti = 0; ti < 2; ++ti)
#pragma unroll
    for (int rr = 0; rr < 4; ++rr)
      m[ti * 4 + rr] = fminf(fminf(acc[ti][0][rr], acc[ti][1][rr]),
                             fminf(acc[ti][2][rr], acc[ti][3][rr]));
#pragma unroll
  for (int o = 1; o < 16; o <<= 1)
#pragma unroll
    for (int s = 0; s < 8; ++s) m[s] = fminf(m[s], __shfl_xor(m[s], o, 64));
  if (lrow == 0)
#pragma unroll
    for (int ti = 0; ti < 2; ++ti)
#pragma unroll
      for (int rr = 0; rr < 4; ++rr)
        red[wave * 32 + ti * 16 + quad * 4 + rr] = m[ti * 4 + rr];
  __syncthreads();
  if (t < 32) {
    float v = red[t];
#pragma unroll
    for (int j = 1; j < 8; ++j) v = fminf(v, red[j * 32 + t]);
    fin[t] = v;
  }
  __syncthreads();

  float sm[8];
#pragma unroll
  for (int ti = 0; ti < 2; ++ti)
#pragma unroll
    for (int rr = 0; rr < 4; ++rr) {
      const float mn = fin[ti * 16 + quad * 4 + rr];
      float s = 0.f;
#pragma unroll
      for (int tj = 0; tj < 4; ++tj) {
        const float e = __expf(mn - acc[ti][tj][rr]);
        acc[ti][tj][rr] = e;
        s += e;
      }
      sm[ti * 4 + rr] = s;
    }
#pragma unroll
  for (int o = 1; o < 16; o <<= 1)
#pragma unroll
    for (int s = 0; s < 8; ++s) sm[s] += __shfl_xor(sm[s], o, 64);
  if (lrow == 0)
#pragma unroll
    for (int ti = 0; ti < 2; ++ti)
#pragma unroll
      for (int rr = 0; rr < 4; ++rr)
        red[wave * 32 + ti * 16 + quad * 4 + rr] = sm[ti * 4 + rr];
  __syncthreads();
  if (t < 32) {
    float v = 0.f;
#pragma unroll
    for (int j = 0; j < 8; ++j) v += red[j * 32 + t];
    fin[t] = 1.0f / v;
  }
  __syncthreads();

  // scale + write fp16 A rows to GLOBAL (linear; glds re-stage pre-swizzles
  // the source).  32 KB per block -> L2-hot, same-CU read-back.
#pragma unroll
  for (int ti = 0; ti < 2; ++ti)
#pragma unroll
    for (int rr = 0; rr < 4; ++rr) {
      const float inv = fin[ti * 16 + quad * 4 + rr];
      const int rl = ti * 16 + quad * 4 + rr;             // local row 0..31
#pragma unroll
      for (int tj = 0; tj < 4; ++tj) {
        const int gcol = wave * 64 + tj * 16 + lrow;
        Ag[(size_t)rl * C + gcol] = f32_to_f16u(acc[ti][tj][rr] * inv);
      }
    }
  asm volatile("s_waitcnt vmcnt(0)" ::: "memory");   // A stores retired to L2
  __syncthreads();                                   // visible to all waves

  // ======================= Phase 2: E = A*F, out = beta*E + x ================
  // 2 column-half passes of 512.  B: xfT rows staged (as phase 1).  A: 32x32
  // slice glds-staged into Asb (waves 0-1, 1 KB each); same swizzle family.
  const float bv = beta[0];

  for (int jp = 0; jp < 2; ++jp) {
    f32x4 eacc[2][4] = {};
#define STAGE2(k0, nb)                                                         \
    {                                                                          \
      _Pragma("unroll")                                                        \
      for (int cc = 0; cc < 4; ++cc) {                                         \
        const int chunk = wave * 4 + cc;                                       \
        const int row = chunk * 16 + srow;                                     \
        glds16(FT + (size_t)(jp * 512 + row) * C + (k0) + sel,                 \
               &Pb[nb][chunk * 512]);                                          \
      }                                                                        \
      if (wave < 2)                                                            \
        glds16(Ag + (size_t)(wave * 16 + srow) * C + (k0) + sel,               \
               &Asb[nb][wave * 512]);                                          \
    }

    STAGE2(0, 0);
    for (int u = 0; u < 16; ++u) {
      __syncthreads();                     // stage(u) landed; prev reads done
      if (u + 1 < 16) STAGE2((u + 1) * 32, (u + 1) & 1);
      const unsigned short* __restrict__ Pc = Pb[u & 1];
      const unsigned short* __restrict__ Ac = Asb[u & 1];
      f16x8 ah[2], bh[4];
#pragma unroll
      for (int ti = 0; ti < 2; ++ti) {
        const int r = ti * 16 + lrow;      // A row 0..31
        ah[ti] = *(const f16x8*)&Ac[r * 32 + (quad ^ ((r >> 1) & 3)) * 8];
      }
#pragma unroll
      for (int tj = 0; tj < 4; ++tj) {
        const int r = wave * 64 + tj * 16 + lrow;   // F^T row within half
        bh[tj] = *(const f16x8*)&Pc[r * 32 + (quad ^ ((r >> 1) & 3)) * 8];
      }
      MFMA8(ah, bh, eacc);
    }
#undef STAGE2

    // Epilogue: per-wave LDS transpose in its OWN Pb[0] region (wave-local,
    // scratch == the same chunks this wave stages -> no cross-wave hazard),
    // residual from fp16 xf, nontemporal stores.
    __syncthreads();                       // all K-loop LDS reads done
    float* fs = (float*)&Pb[0][0] + wave * 1024;   // 4 KB per wave
#pragma unroll
    for (int ti = 0; ti < 2; ++ti) {
#pragma unroll
      for (int tj = 0; tj < 4; ++tj)
#pragma unroll
        for (int r = 0; r < 4; ++r)
          fs[(quad * 4 + r) * 64 + tj * 16 + lrow] = eacc[ti][tj][r];
      asm volatile("s_waitcnt lgkmcnt(0)" ::: "memory");   // per-wave RAW fence
#pragma unroll
      for (int p = 0; p < 4; ++p) {
        const int f = p * 64 + lane;
        const int rr2 = f >> 4, cc4 = (f & 15) * 4;
        const f32x4 e = *(const f32x4*)&fs[rr2 * 64 + cc4];
        const int gr = i0 + ti * 16 + rr2;
        const int gc = jp * 512 + wave * 64 + cc4;
        const size_t o = (size_t)gr * N + gc;
        const u16x4 xv = *(const u16x4*)&Fh[o];
        f32x4 ov;
        ov[0] = fmaf(bv, e[0], f16u_to_f32(xv[0]));
        ov[1] = fmaf(bv, e[1], f16u_to_f32(xv[1]));
        ov[2] = fmaf(bv, e[2], f16u_to_f32(xv[2]));
        ov[3] = fmaf(bv, e[3], f16u_to_f32(xv[3]));
        __builtin_nontemporal_store(ov, (f32x4*)&ob[o]);
      }
      asm volatile("s_waitcnt lgkmcnt(0)" ::: "memory");   // reads drained
    }
    // program order per wave: scratch reads drained above BEFORE next jp's
    // glds issue; scratch region == this wave's own staging chunks.
  }
#undef MFMA8
}

// ---------------------------------------------------------------------------
extern "C" void kernel_launch(void* const* d_in, const int* in_sizes, int n_in,
                              void* d_out, int out_size, void* d_ws, size_t ws_size,
                              hipStream_t stream) {
  const float* x    = (const float*)d_in[0];
  const float* beta = (const float*)d_in[1];
  float* out = (float*)d_out;

  char* ws = (char*)d_ws;
  unsigned short* xf  = (unsigned short*)ws; ws += (size_t)B * C * N * 2;  // 32 MB
  unsigned short* xfT = (unsigned short*)ws; ws += (size_t)B * N * C * 2;  // 32 MB
  unsigned short* Aw  = (unsigned short*)ws;                               // 16 MB

  convert_kernel<<<dim3(N / 64, C / 64, B), dim3(256), 0, stream>>>(x, xf, xfT);
  gram_soft_av  <<<dim3(512),               dim3(512), 0, stream>>>(xf, xfT, Aw, beta, out);
}